// Round 8
// baseline (102.114 us; speedup 1.0000x reference)
//
#include <hip/hip_runtime.h>

// ---------------------------------------------------------------------------
// TwoLayerGCN on MI355X (gfx950).  B=4, N=2048, F=128, H=256, C=64.
//
//   d_i = rsqrt(nnz_i + 1) ; w_ij = [A_ij>0] exp(lrelu(fs_i+fd_j)) d_j (1+[i==j])
//   rs_i = sum_j [A_ij>0] exp(lrelu(fs_i+fd_j))
//   layer1: out1 = relu( (d_i/rs_i)(W@X)@W1 + b1 )
//   layer2: node = (d_i/rs_i) W2mat@(out1@W2) + b2 ; graph = sum_i node
//
// R5-R7: CSR row-gather SpMM (A ~9.75% dense); CSR built during the one A read.
// R8: the per-64-chunk w-stage was a serial bubble (irow global load ->
// 64-line FDD scatter -> exp2 -> ds_write before any FMA). Now: (fd,d) panel
// (16KB/batch) preloaded to LDS; chunk pipeline = {w-compute(VALU) ->
// issue next irow -> q-loop -> fdp LDS gather}; kgat1 rows split across
// 2 waves (halved chain, 2 block generations).
// ---------------------------------------------------------------------------

typedef __attribute__((ext_vector_type(8))) short  s16x8;
typedef __attribute__((ext_vector_type(4))) float  f32x4;
typedef unsigned short u16;
typedef unsigned int   u32;
typedef unsigned long long u64;

#define LOG2E 1.4426950408889634f
#define NB 4
#define NN 2048
#define NF 128
#define NH 256
#define NC 64
#define CST 320            // CSR row stride in u16 (max deg ~254)

__device__ __forceinline__ u16 f2bf(float f) {
    u32 x = __builtin_bit_cast(u32, f);
    return (u16)((x + 0x7fffu + ((x >> 16) & 1u)) >> 16);
}
__device__ __forceinline__ float bflo(u32 x) {
    return __builtin_bit_cast(float, x << 16);
}
__device__ __forceinline__ float bfhi(u32 x) {
    return __builtin_bit_cast(float, x & 0xffff0000u);
}
__device__ __forceinline__ u32 mbcnt64(u64 m) {
    return __builtin_amdgcn_mbcnt_hi((u32)(m >> 32),
           __builtin_amdgcn_mbcnt_lo((u32)m, 0));
}

// ---- kpre: block-role dispatch ---------------------------------------------
__global__ void kpre(const float* __restrict__ X, const float* __restrict__ A,
                     const float* __restrict__ a1s, const float* __restrict__ a1d,
                     const float* __restrict__ W1, const float* __restrict__ W2,
                     u16* __restrict__ Xbf, u16* __restrict__ W1T,
                     u16* __restrict__ W2T, float* __restrict__ FS1,
                     float* __restrict__ FDD1, float* __restrict__ FDD2,
                     int* __restrict__ cnt, u16* __restrict__ idx) {
    const int bid = blockIdx.x;
    const int t = threadIdx.x;
    if (bid >= NB * 64 + 4) {                 // ---- stats role ----
        __shared__ u64 masks[32];
        __shared__ u32 basep[33];
        int row = bid - (NB * 64 + 4);        // 0..8191
        const float* Arow = A + (size_t)row * NN;
        int l = t & 63, wv = t >> 6;
#pragma unroll
        for (int e = 0; e < 8; e++) {
            float a = Arow[e * 256 + t];
            u64 m = __ballot(a > 0.f);
            if (l == 0) masks[e * 4 + wv] = m;
        }
        __syncthreads();
        if (t == 0) {
            u32 s = 0;
#pragma unroll
            for (int m = 0; m < 32; m++) { basep[m] = s; s += __popcll(masks[m]); }
            basep[32] = s;
            cnt[row] = (int)s;
            float d = rsqrtf((float)s + 1.0f);
            FDD1[2 * row + 1] = d;
            FDD2[2 * row + 1] = d;
        }
        __syncthreads();
#pragma unroll
        for (int s = 0; s < 8; s++) {
            int mi = wv * 8 + s;
            u64 m = masks[mi];
            if ((m >> l) & 1ull)
                idx[(size_t)row * CST + basep[mi] + mbcnt64(m)] = (u16)(mi * 64 + l);
        }
        return;
    }
    if (bid >= NB * 64) {                     // ---- weight role ----
        int tt = (bid - NB * 64) * 256 + t;
        for (int i = tt; i < NF * NH; i += 1024) {
            int k = i >> 8, c = i & 255;
            W1T[c * NF + k] = f2bf(W1[i]);
        }
        for (int i = tt; i < NH * NC; i += 1024) {
            int k = i >> 6, c = i & 63;
            W2T[c * NH + k] = f2bf(W2[i]);
        }
        return;
    }
    // ---- X role: 32 rows ----
    __shared__ float tile[32][132];
    __shared__ float asb[NF], adb[NF];
    __shared__ float dred[32][8][2];
    const int b = bid >> 6, i0 = (bid & 63) * 32;
    if (t < 128) asb[t] = a1s[t];
    else         adb[t - 128] = a1d[t - 128];
    for (int i = t; i < 32 * NF; i += 256) {
        int r = i >> 7, c = i & 127;
        tile[r][c] = X[((size_t)b * NN + i0 + r) * NF + c];
    }
    __syncthreads();
    {   // layer1 dots
        int r = t >> 3, ch = t & 7;
        float ps = 0.f, pd = 0.f;
#pragma unroll
        for (int q = 0; q < 16; q++) {
            float x = tile[r][ch * 16 + q];
            ps += x * asb[ch * 16 + q];
            pd += x * adb[ch * 16 + q];
        }
        dred[r][ch][0] = ps; dred[r][ch][1] = pd;
    }
    {   // Xbf row-major bf16
        int r = t >> 3, c = (t & 7) * 16;
        __attribute__((aligned(16))) u16 tmp[16];
#pragma unroll
        for (int q = 0; q < 16; q++) tmp[q] = f2bf(tile[r][c + q]);
        int4* dst = (int4*)&Xbf[((size_t)b * NN + i0 + r) * NF + c];
        const int4* sv = (const int4*)tmp;
        dst[0] = sv[0]; dst[1] = sv[1];
    }
    __syncthreads();
    if (t < 64) {
        int r = t & 31, which = t >> 5;
        float s = 0.f;
#pragma unroll
        for (int ch = 0; ch < 8; ch++) s += dred[r][ch][which];
        int grow = (b << 11) + i0 + r;
        if (which == 0) FS1[grow] = s * LOG2E;
        else            FDD1[2 * grow] = s * LOG2E;
    }
}

#define FMA8(W_, XV) { \
    float w_ = __builtin_bit_cast(float, W_); \
    accA[0] += w_ * bflo(XV.x); accA[1] += w_ * bfhi(XV.x); \
    accA[2] += w_ * bflo(XV.y); accA[3] += w_ * bfhi(XV.y); \
    accB[0] += w_ * bflo(XV.z); accB[1] += w_ * bfhi(XV.z); \
    accB[2] += w_ * bflo(XV.w); accB[3] += w_ * bfhi(XV.w); }

// ---- kgat1: gather layer1 (2 waves/row) + fused T@W1, dots2, out1@W2 -------
__global__ __launch_bounds__(512) void kgat1(
    const u16* __restrict__ idx, const int* __restrict__ cnt,
    const float* __restrict__ FS, const float* __restrict__ FDD,
    const u16* __restrict__ Xbf, const u16* __restrict__ W1T,
    const u16* __restrict__ W2T, const float* __restrict__ b1,
    const float* __restrict__ a2s, const float* __restrict__ a2d,
    float* __restrict__ FS2, float* __restrict__ FDD2,
    u16* __restrict__ OW2row) {
    const int b = blockIdx.y;
    const int i0 = blockIdx.x * 4;
    const int t = threadIdx.x, wv = t >> 6, l = t & 63;
    const int g = l >> 4, li = l & 15;
    const int qw = l >> 4, ql = l & 15;
    const int ri = wv >> 1, hh = wv & 1;

    __shared__ __attribute__((aligned(16))) char usm[16640];   // fdp | o1
    float2* fdp = (float2*)usm;                                // [2048]
    float*  o1  = (float*)usm;                                 // [16][260]
    __shared__ uint2 wlds[8][64];
    __shared__ __attribute__((aligned(16))) u16 tlds[16][136];
    __shared__ float cmb[4][2][16][8];
    __shared__ float rscmb[4][2];

    for (int z = t; z < 12 * 136; z += 512)     // zero pad rows 4..15 of T'
        ((u16*)tlds)[4 * 136 + z] = 0;

    const int row = i0 + ri;
    const int grow = (b << 11) + row;
    const float fs = FS[grow];
    const float* FDDb = FDD + ((size_t)(b << 11) << 1);
    const u16* irow = idx + (size_t)grow * CST;
    const int cn = cnt[grow];
    const char* Xb = (const char*)(Xbf + (size_t)b * NN * NF);

    // stage FDD panel (2048 float2 = 16KB): 512 thr x 2 float4
    {
        const float4* src = (const float4*)FDDb;
        float4* dst = (float4*)usm;
        dst[t] = src[t];
        dst[t + 512] = src[t + 512];
    }

    f32x4 accA = {0.f, 0.f, 0.f, 0.f}, accB = {0.f, 0.f, 0.f, 0.f};
    float rs = 0.f;
    int p0 = hh << 6;
    int jC = 0; float2 fddC = {0.f, 0.f}; bool vC = false;
    if (p0 < cn) {                              // prolog irow (pre-barrier)
        int p = min(p0 + l, cn - 1);
        jC = irow[p];
    }
    __syncthreads();                            // panel ready
    if (p0 < cn) { fddC = fdp[jC]; vC = p0 + l < cn; }

    for (; p0 < cn; p0 += 128) {
        float s = fs + fddC.x;
        float e = exp2f(fmaxf(s, 0.2f * s));
        e = vC ? e : 0.f;
        rs += e;
        float w = e * fddC.y * ((jC == row) ? 2.f : 1.f);
        wlds[wv][l] = (uint2){__builtin_bit_cast(u32, w), (u32)jC * (NF * 2)};
        const int np = p0 + 128;
        int jN = 0;
        if (np < cn) { int p = min(np + l, cn - 1); jN = irow[p]; }  // hidden
        int nq = min(64, cn - p0);
        for (int q = 0; q < nq; q += 16) {
            uint2 c0 = wlds[wv][q + qw];
            uint2 c1 = wlds[wv][q + 4 + qw];
            uint2 c2 = wlds[wv][q + 8 + qw];
            uint2 c3 = wlds[wv][q + 12 + qw];
            uint4 x0 = *(const uint4*)(Xb + c0.y + ql * 16);
            uint4 x1 = *(const uint4*)(Xb + c1.y + ql * 16);
            uint4 x2 = *(const uint4*)(Xb + c2.y + ql * 16);
            uint4 x3 = *(const uint4*)(Xb + c3.y + ql * 16);
            FMA8(c0.x, x0);
            FMA8(c1.x, x1);
            FMA8(c2.x, x2);
            FMA8(c3.x, x3);
        }
        if (np < cn) { fddC = fdp[jN]; jC = jN; vC = np + l < cn; }
    }
#pragma unroll
    for (int r = 0; r < 4; r++) {
        accA[r] += __shfl_xor(accA[r], 16); accA[r] += __shfl_xor(accA[r], 32);
        accB[r] += __shfl_xor(accB[r], 16); accB[r] += __shfl_xor(accB[r], 32);
    }
#pragma unroll
    for (int o = 1; o < 64; o <<= 1) rs += __shfl_xor(rs, o);
    if (qw == 0) {
#pragma unroll
        for (int r = 0; r < 4; r++) {
            cmb[ri][hh][ql][r]     = accA[r];
            cmb[ri][hh][ql][4 + r] = accB[r];
        }
    }
    if (l == 0) rscmb[ri][hh] = rs;
    __syncthreads();
    if (t < 64) {     // combine halves -> T' rows 0..3 (rsc pre-applied bf16)
        int rr = t >> 4, q = t & 15;
        float rsum = rscmb[rr][0] + rscmb[rr][1];
        float rsc = FDDb[2 * (i0 + rr) + 1] / fmaxf(rsum, 1e-30f);
        float a[8];
#pragma unroll
        for (int f = 0; f < 8; f++)
            a[f] = (cmb[rr][0][q][f] + cmb[rr][1][q][f]) * rsc;
        uint4 pk;
        pk.x = (u32)f2bf(a[0]) | ((u32)f2bf(a[1]) << 16);
        pk.y = (u32)f2bf(a[2]) | ((u32)f2bf(a[3]) << 16);
        pk.z = (u32)f2bf(a[4]) | ((u32)f2bf(a[5]) << 16);
        pk.w = (u32)f2bf(a[6]) | ((u32)f2bf(a[7]) << 16);
        *(uint4*)&tlds[rr][q * 8] = pk;
    }
    __syncthreads();
    // GEMM1: o1[4pad16][256] = T' @ W1 ; wave = 32 cols
    f32x4 zero = {0.f, 0.f, 0.f, 0.f};
    f32x4 p0a = zero, p1a = zero;
#pragma unroll
    for (int k2 = 0; k2 < 4; k2++) {
        s16x8 af = *(const s16x8*)&tlds[li][k2 * 32 + g * 8];
        s16x8 w0 = *(const s16x8*)&W1T[(size_t)(wv * 32 + li) * NF + k2 * 32 + g * 8];
        s16x8 w1 = *(const s16x8*)&W1T[(size_t)(wv * 32 + 16 + li) * NF + k2 * 32 + g * 8];
        p0a = __builtin_amdgcn_mfma_f32_16x16x32_bf16(af, w0, p0a, 0, 0, 0);
        p1a = __builtin_amdgcn_mfma_f32_16x16x32_bf16(af, w1, p1a, 0, 0, 0);
    }
    __syncthreads();           // fdp dead -> o1 region reusable
#pragma unroll
    for (int r = 0; r < 4; r++) {   // rows g*4+r; g>=1 are pad rows -> 0
        int rr = g * 4 + r;
        int ca = wv * 32 + li, cb = ca + 16;
        o1[rr * 260 + ca] = (g == 0) ? fmaxf(p0a[r] + b1[ca], 0.f) : 0.f;
        o1[rr * 260 + cb] = (g == 0) ? fmaxf(p1a[r] + b1[cb], 0.f) : 0.f;
    }
    __syncthreads();
    if (wv >= 4) {     // dots2: wave handles row wv-4; 4 feats/lane
        int r = wv - 4;
        int c = l * 4;
        float4 xv = *(const float4*)&o1[r * 260 + c];
        float4 sv = *(const float4*)&a2s[c];
        float4 dv = *(const float4*)&a2d[c];
        float ps = xv.x * sv.x + xv.y * sv.y + xv.z * sv.z + xv.w * sv.w;
        float pd = xv.x * dv.x + xv.y * dv.y + xv.z * dv.z + xv.w * dv.w;
#pragma unroll
        for (int o = 1; o < 64; o <<= 1) {
            ps += __shfl_xor(ps, o); pd += __shfl_xor(pd, o);
        }
        if (l == 0) {
            FS2[(b << 11) + i0 + r]        = ps * LOG2E;
            FDD2[2 * ((b << 11) + i0 + r)] = pd * LOG2E;
        }
    } else {           // GEMM2: OW2row[4][64] = o1 @ W2 ; wave = 16 cols
        f32x4 q0 = zero;
#pragma unroll
        for (int k2 = 0; k2 < 8; k2++) {
            const float* op = &o1[li * 260 + k2 * 32 + g * 8];
            float4 v0 = *(const float4*)op;
            float4 v1 = *(const float4*)(op + 4);
            s16x8 aa;
            aa[0] = (short)f2bf(v0.x); aa[1] = (short)f2bf(v0.y);
            aa[2] = (short)f2bf(v0.z); aa[3] = (short)f2bf(v0.w);
            aa[4] = (short)f2bf(v1.x); aa[5] = (short)f2bf(v1.y);
            aa[6] = (short)f2bf(v1.z); aa[7] = (short)f2bf(v1.w);
            s16x8 bb = *(const s16x8*)&W2T[(size_t)(wv * 16 + li) * NH + k2 * 32 + g * 8];
            q0 = __builtin_amdgcn_mfma_f32_16x16x32_bf16(aa, bb, q0, 0, 0, 0);
        }
        if (g == 0) {
#pragma unroll
            for (int r = 0; r < 4; r++)
                OW2row[((size_t)(b << 11) + i0 + r) * NC + wv * 16 + li] = f2bf(q0[r]);
        }
    }
}

// ---- kgat2: gather layer2 on OW2 rows; node + graph partials ---------------
__global__ __launch_bounds__(512) void kgat2(
    const u16* __restrict__ idx, const int* __restrict__ cnt,
    const float* __restrict__ FS, const float* __restrict__ FDD,
    const u16* __restrict__ OW2row, const float* __restrict__ b2,
    float* __restrict__ node, float* __restrict__ gpart) {
    const int b = blockIdx.y;
    const int i0 = blockIdx.x * 8;
    const int t = threadIdx.x, wv = t >> 6, l = t & 63;
    const int ow = l >> 3, ol = l & 7;
    __shared__ __attribute__((aligned(16))) float2 fdp[2048];   // 16 KB
    __shared__ uint2 wlds[8][64];
    __shared__ float gsm[8][64];

    const int row = i0 + wv;
    const int grow = (b << 11) + row;
    const float fs = FS[grow];
    const float* FDDb = FDD + ((size_t)(b << 11) << 1);
    const u16* irow = idx + (size_t)grow * CST;
    const int cn = cnt[grow];
    const char* Ob = (const char*)(OW2row + (size_t)(b << 11) * NC);

    {
        const float4* src = (const float4*)FDDb;
        float4* dst = (float4*)fdp;
        dst[t] = src[t];
        dst[t + 512] = src[t + 512];
    }

    f32x4 accA = {0.f, 0.f, 0.f, 0.f}, accB = {0.f, 0.f, 0.f, 0.f};
    float rs = 0.f;
    int jC = 0; float2 fddC = {0.f, 0.f}; bool vC = false;
    {
        int p = min(l, max(cn - 1, 0));
        jC = irow[p];
    }
    __syncthreads();
    if (cn > 0) { fddC = fdp[jC]; vC = l < cn; }

    for (int p0 = 0; p0 < cn; p0 += 64) {
        float s = fs + fddC.x;
        float e = exp2f(fmaxf(s, 0.2f * s));
        e = vC ? e : 0.f;
        rs += e;
        float w = e * fddC.y * ((jC == row) ? 2.f : 1.f);
        wlds[wv][l] = (uint2){__builtin_bit_cast(u32, w), (u32)jC * (NC * 2)};
        const int np = p0 + 64;
        int jN = 0;
        if (np < cn) { int p = min(np + l, cn - 1); jN = irow[p]; }
        int nq = min(64, cn - p0);
        for (int q = 0; q < nq; q += 16) {
            uint2 c0 = wlds[wv][q + ow];
            uint2 c1 = wlds[wv][q + 8 + ow];
            uint4 x0 = *(const uint4*)(Ob + c0.y + ol * 16);
            uint4 x1 = *(const uint4*)(Ob + c1.y + ol * 16);
            FMA8(c0.x, x0);
            FMA8(c1.x, x1);
        }
        if (np < cn) { fddC = fdp[jN]; jC = jN; vC = np + l < cn; }
    }
#pragma unroll
    for (int r = 0; r < 4; r++) {
        accA[r] += __shfl_xor(accA[r], 8);
        accA[r] += __shfl_xor(accA[r], 16); accA[r] += __shfl_xor(accA[r], 32);
        accB[r] += __shfl_xor(accB[r], 8);
        accB[r] += __shfl_xor(accB[r], 16); accB[r] += __shfl_xor(accB[r], 32);
    }
#pragma unroll
    for (int o = 1; o < 64; o <<= 1) rs += __shfl_xor(rs, o);
    float rsc = FDDb[2 * row + 1] / fmaxf(rs, 1e-30f);
    if (ow == 0) {     // lane ol: feats ol*8..+7
        int c = ol * 8;
        float4 b2a = *(const float4*)&b2[c];
        float4 b2b = *(const float4*)&b2[c + 4];
        float4 va = {accA[0] * rsc + b2a.x, accA[1] * rsc + b2a.y,
                     accA[2] * rsc + b2a.z, accA[3] * rsc + b2a.w};
        float4 vb = {accB[0] * rsc + b2b.x, accB[1] * rsc + b2b.y,
                     accB[2] * rsc + b2b.z, accB[3] * rsc + b2b.w};
        *(float4*)&node[(size_t)grow * NC + c]     = va;
        *(float4*)&node[(size_t)grow * NC + c + 4] = vb;
        *(float4*)&gsm[wv][c]     = va;
        *(float4*)&gsm[wv][c + 4] = vb;
    }
    __syncthreads();
    if (t < NC) {
        float s = 0.f;
#pragma unroll
        for (int r = 0; r < 8; r++) s += gsm[r][t];
        gpart[(((size_t)b * (NN / 8)) + blockIdx.x) * NC + t] = s;
    }
}

// ---- graph scores: reduce per-block partials -------------------------------
__global__ void kgraph2(const float* __restrict__ gpart, float* __restrict__ graph) {
    int b = blockIdx.x;
    int c = threadIdx.x & 63, ch = threadIdx.x >> 6;
    float s = 0.f;
    for (int p = ch; p < NN / 8; p += 4)
        s += gpart[(((size_t)b * (NN / 8)) + p) * NC + c];
    __shared__ float red[4][64];
    red[ch][c] = s;
    __syncthreads();
    if (ch == 0) graph[b * NC + c] = red[0][c] + red[1][c] + red[2][c] + red[3][c];
}

extern "C" void kernel_launch(void* const* d_in, const int* in_sizes, int n_in,
                              void* d_out, int out_size, void* d_ws, size_t ws_size,
                              hipStream_t stream) {
    const float* X   = (const float*)d_in[0];
    const float* A   = (const float*)d_in[1];
    const float* a1s = (const float*)d_in[2];
    const float* a1d = (const float*)d_in[3];
    const float* W1  = (const float*)d_in[4];
    const float* b1  = (const float*)d_in[5];
    const float* a2s = (const float*)d_in[6];
    const float* a2d = (const float*)d_in[7];
    const float* W2  = (const float*)d_in[8];
    const float* b2  = (const float*)d_in[9];

    float* node  = (float*)d_out;                 // [4][2048][64]
    float* graph = node + (size_t)NB * NN * NC;   // [4][64]

    char* w = (char*)d_ws;
    float* FS1  = (float*)w; w += NB * NN * 4;
    float* FDD1 = (float*)w; w += NB * NN * 8;    // (fd1_j, d_j) pairs
    float* FS2  = (float*)w; w += NB * NN * 4;
    float* FDD2 = (float*)w; w += NB * NN * 8;    // (fd2_j, d_j) pairs
    int*  cntv  = (int*)w;  w += NB * NN * 4;
    float* gpart = (float*)w; w += (size_t)NB * (NN / 8) * NC * 4;   // 256 KB
    u16*  Xbf   = (u16*)w;  w += (size_t)NB * NN * NF * 2;           // 2 MB
    u16*  OW2row = (u16*)w; w += (size_t)NB * NN * NC * 2;           // 1 MB
    u16*  W1T   = (u16*)w;  w += NH * NF * 2;
    u16*  W2T   = (u16*)w;  w += NC * NH * 2;
    u16*  idx   = (u16*)w;  w += (size_t)NB * NN * CST * 2;          // 5.25 MB

    kpre    <<<NB * 64 + 4 + NB * NN, 256, 0, stream>>>(X, A, a1s, a1d, W1, W2,
                                                        Xbf, W1T, W2T, FS1,
                                                        FDD1, FDD2, cntv, idx);
    kgat1   <<<dim3(NN / 4, NB), 512, 0, stream>>>(idx, cntv, FS1, FDD1, Xbf,
                                                   W1T, W2T, b1, a2s, a2d,
                                                   FS2, FDD2, OW2row);
    kgat2   <<<dim3(NN / 8, NB), 512, 0, stream>>>(idx, cntv, FS2, FDD2,
                                                   OW2row, b2, node, gpart);
    kgraph2 <<<NB, 256, 0, stream>>>(gpart, graph);
}

// Round 9
// 76.045 us; speedup vs baseline: 1.3428x; 1.3428x over previous
//
#include <hip/hip_runtime.h>

// ---------------------------------------------------------------------------
// TwoLayerGCN on MI355X (gfx950).  B=4, N=2048, F=128, H=256, C=64.
//
//   d_i = rsqrt(nnz_i + 1) ; w_ij = [A_ij>0] exp(lrelu(fs_i+fd_j)) d_j (1+[i==j])
//   rs_i = sum_j [A_ij>0] exp(lrelu(fs_i+fd_j))
//   layer1: out1 = relu( (d_i/rs_i)(W@X)@W1 + b1 )
//   layer2: node = (d_i/rs_i) W2mat@(out1@W2) + b2 ; graph = sum_i node
//
// R9: back to dense MFMA SpMM but with ZERO barriers in the K-loop:
//   - operand swap: A = XT (M=features), B = w (N=output rows). Each lane
//     computes its own B-frag w-values in registers (fs_i per-lane const;
//     fd_j/d_j via broadcast LDS reads; mask byte via conflict-free LDS tile).
//   - XT fragments loaded directly from global (L2-resident panels).
//   - waves split K (4-way x feat 2-way layer1; 8-way layer2); one end-of-loop
//     LDS slab reduction (single barrier) instead of per-step barriers.
//   - R4's verified epilogue (T@W1 -> o1 -> dots2 + out1@W2 -> OW2T) kept.
// ---------------------------------------------------------------------------

typedef __attribute__((ext_vector_type(8))) short  s16x8;
typedef __attribute__((ext_vector_type(4))) float  f32x4;
typedef unsigned short u16;
typedef unsigned int   u32;
typedef unsigned long long u64;

#define LOG2E 1.4426950408889634f
#define NB 4
#define NN 2048
#define NF 128
#define NH 256
#define NC 64

__device__ __forceinline__ u16 f2bf(float f) {
    u32 x = __builtin_bit_cast(u32, f);
    return (u16)((x + 0x7fffu + ((x >> 16) & 1u)) >> 16);
}

// ---- kpre: block-role dispatch ---------------------------------------------
// [0,256): X-tiles -> XT (bf16, [feat][node]) + layer1 dots (FS1, FDD1.x).
// [256,260): W1T/W2T transposes.
// [260,260+8192): stats: A read -> bm bitmask, deg -> FDD1.y & FDD2.y.
__global__ void kpre(const float* __restrict__ X, const float* __restrict__ A,
                     const float* __restrict__ a1s, const float* __restrict__ a1d,
                     const float* __restrict__ W1, const float* __restrict__ W2,
                     u16* __restrict__ XT, u16* __restrict__ W1T,
                     u16* __restrict__ W2T, float* __restrict__ FS1,
                     float* __restrict__ FDD1, float* __restrict__ FDD2,
                     u64* __restrict__ bm) {
    const int bid = blockIdx.x;
    const int t = threadIdx.x;
    if (bid >= NB * 64 + 4) {                 // ---- stats role ----
        __shared__ u64 masks[32];
        int row = bid - (NB * 64 + 4);        // 0..8191
        const float* Arow = A + (size_t)row * NN;
        int l = t & 63, wv = t >> 6;
#pragma unroll
        for (int e = 0; e < 8; e++) {
            float a = Arow[e * 256 + t];
            u64 m = __ballot(a > 0.f);
            if (l == 0) { masks[e * 4 + wv] = m; bm[(size_t)row * 32 + e * 4 + wv] = m; }
        }
        __syncthreads();
        if (t == 0) {
            u32 s = 0;
#pragma unroll
            for (int m = 0; m < 32; m++) s += __popcll(masks[m]);
            float d = rsqrtf((float)s + 1.0f);
            FDD1[2 * row + 1] = d;
            FDD2[2 * row + 1] = d;
        }
        return;
    }
    if (bid >= NB * 64) {                     // ---- weight role ----
        int tt = (bid - NB * 64) * 256 + t;
        for (int i = tt; i < NF * NH; i += 1024) {
            int k = i >> 8, c = i & 255;
            W1T[c * NF + k] = f2bf(W1[i]);
        }
        for (int i = tt; i < NH * NC; i += 1024) {
            int k = i >> 6, c = i & 63;
            W2T[c * NH + k] = f2bf(W2[i]);
        }
        return;
    }
    // ---- X role: 32 rows ----
    __shared__ float tile[32][132];
    __shared__ float asb[NF], adb[NF];
    __shared__ float dred[32][8][2];
    const int b = bid >> 6, i0 = (bid & 63) * 32;
    if (t < 128) asb[t] = a1s[t];
    else         adb[t - 128] = a1d[t - 128];
    for (int i = t; i < 32 * NF; i += 256) {
        int r = i >> 7, c = i & 127;
        tile[r][c] = X[((size_t)b * NN + i0 + r) * NF + c];
    }
    __syncthreads();
    {   // layer1 dots
        int r = t >> 3, ch = t & 7;
        float ps = 0.f, pd = 0.f;
#pragma unroll
        for (int q = 0; q < 16; q++) {
            float x = tile[r][ch * 16 + q];
            ps += x * asb[ch * 16 + q];
            pd += x * adb[ch * 16 + q];
        }
        dred[r][ch][0] = ps; dred[r][ch][1] = pd;
    }
    {   // XT transpose: c = t>>1 (feat 0..127), half = t&1 (16 rows)
        int c = t >> 1, half = t & 1;
        __attribute__((aligned(16))) u16 tmp[16];
#pragma unroll
        for (int q = 0; q < 16; q++) tmp[q] = f2bf(tile[half * 16 + q][c]);
        int4* dst = (int4*)&XT[((size_t)b * NF + c) * NN + i0 + half * 16];
        const int4* sv = (const int4*)tmp;
        dst[0] = sv[0]; dst[1] = sv[1];
    }
    __syncthreads();
    if (t < 64) {
        int r = t & 31, which = t >> 5;
        float s = 0.f;
#pragma unroll
        for (int ch = 0; ch < 8; ch++) s += dred[r][ch][which];
        int grow = (b << 11) + i0 + r;
        if (which == 0) FS1[grow] = s * LOG2E;
        else            FDD1[2 * grow] = s * LOG2E;
    }
}

// w B-fragment: 8 w values for row IR (batch-local), j = jb..jb+7.
#define MKW(FS_, IR_, M_, BW_, RS_) { \
    float fd_[8] = {f0.x, f0.z, f1.x, f1.z, f2v.x, f2v.z, f3v.x, f3v.z}; \
    float dd_[8] = {f0.y, f0.w, f1.y, f1.w, f2v.y, f2v.w, f3v.y, f3v.w}; \
    _Pragma("unroll") \
    for (int e = 0; e < 8; e++) { \
        float s_ = FS_ + fd_[e]; \
        float e_ = exp2f(fmaxf(s_, 0.2f * s_)); \
        bool mk = (M_ >> e) & 1u; \
        RS_ += mk ? e_ : 0.f; \
        float w_ = e_ * dd_[e]; \
        if (jb + e == IR_) w_ *= 2.f; \
        BW_[e] = mk ? (short)f2bf(w_) : (short)0; } }

// ---- kdense1: layer1 SpMM (no-barrier K-loop) + R4 epilogue ----------------
__global__ __launch_bounds__(512) void kdense1(
    const u64* __restrict__ bm, const float* __restrict__ FS,
    const float* __restrict__ FDD, const u16* __restrict__ XT,
    const u16* __restrict__ W1T, const u16* __restrict__ W2T,
    const float* __restrict__ b1, const float* __restrict__ a2s,
    const float* __restrict__ a2d, float* __restrict__ FS2,
    float* __restrict__ FDD2, u16* __restrict__ OW2T) {
    const int b = blockIdx.y;
    const int i0 = blockIdx.x * 32;
    const int t = threadIdx.x, wv = t >> 6, l = t & 63;
    const int li = l & 15, q = l >> 4;
    const int kf = wv >> 1, ff = wv & 1;

    __shared__ __attribute__((aligned(16))) float tpart[4][32][132];  // 67.6KB
    float* o1 = &tpart[2][0][0];            // [32][260] aliases tpart[2..3]
    __shared__ __attribute__((aligned(16))) float2 fdp[2048];         // 16KB
    __shared__ __attribute__((aligned(16))) u32 bmt[32][68];          // 8.7KB
    __shared__ float rsred[4][2][16];
    __shared__ float rscl[32];
    __shared__ float dredp[1024];

    const float* FDDb = FDD + ((size_t)(b << 11) << 1);
    {   // stage fd/d panel
        const float4* src = (const float4*)FDDb;
        float4* dst = (float4*)fdp;
        dst[t] = src[t]; dst[t + 512] = src[t + 512];
    }
    {   // stage bm tile: 32 rows x 256B, padded stride 68 u32
        int r = t >> 4, seg = t & 15;
        const uint4* src = (const uint4*)(bm + ((size_t)((b << 11) + i0 + r)) * 32);
        *(uint4*)&bmt[r][seg * 4] = src[seg];
    }
    __syncthreads();

    const float fs0 = FS[(b << 11) + i0 + li];
    const float fs1 = FS[(b << 11) + i0 + 16 + li];
    const int irow0 = i0 + li, irow1 = i0 + 16 + li;
    const u16* XTb = XT + (size_t)b * NF * NN;
    const u16* xbase = XTb + (size_t)(ff * 64 + li) * NN + q * 8;

    f32x4 zero = {0.f, 0.f, 0.f, 0.f};
    f32x4 acc[4][2];
#pragma unroll
    for (int fa = 0; fa < 4; fa++) { acc[fa][0] = zero; acc[fa][1] = zero; }
    float rs0 = 0.f, rs1 = 0.f;

    for (int s = 0; s < 16; ++s) {
        const int kb = (kf * 16 + s) * 32;
        s16x8 xa0 = *(const s16x8*)(xbase + kb);
        s16x8 xa1 = *(const s16x8*)(xbase + (size_t)16 * NN + kb);
        s16x8 xa2 = *(const s16x8*)(xbase + (size_t)32 * NN + kb);
        s16x8 xa3 = *(const s16x8*)(xbase + (size_t)48 * NN + kb);
        const float4* fp4 = (const float4*)&fdp[kb + q * 8];
        float4 f0 = fp4[0], f1 = fp4[1], f2v = fp4[2], f3v = fp4[3];
        u32 m0 = (bmt[li][kb >> 5]      >> (q * 8)) & 0xffu;
        u32 m1 = (bmt[16 + li][kb >> 5] >> (q * 8)) & 0xffu;
        const int jb = kb + q * 8;
        s16x8 bw0, bw1;
        MKW(fs0, irow0, m0, bw0, rs0);
        MKW(fs1, irow1, m1, bw1, rs1);
        acc[0][0] = __builtin_amdgcn_mfma_f32_16x16x32_bf16(xa0, bw0, acc[0][0], 0, 0, 0);
        acc[1][0] = __builtin_amdgcn_mfma_f32_16x16x32_bf16(xa1, bw0, acc[1][0], 0, 0, 0);
        acc[2][0] = __builtin_amdgcn_mfma_f32_16x16x32_bf16(xa2, bw0, acc[2][0], 0, 0, 0);
        acc[3][0] = __builtin_amdgcn_mfma_f32_16x16x32_bf16(xa3, bw0, acc[3][0], 0, 0, 0);
        acc[0][1] = __builtin_amdgcn_mfma_f32_16x16x32_bf16(xa0, bw1, acc[0][1], 0, 0, 0);
        acc[1][1] = __builtin_amdgcn_mfma_f32_16x16x32_bf16(xa1, bw1, acc[1][1], 0, 0, 0);
        acc[2][1] = __builtin_amdgcn_mfma_f32_16x16x32_bf16(xa2, bw1, acc[2][1], 0, 0, 0);
        acc[3][1] = __builtin_amdgcn_mfma_f32_16x16x32_bf16(xa3, bw1, acc[3][1], 0, 0, 0);
    }
    rs0 += __shfl_xor(rs0, 16); rs0 += __shfl_xor(rs0, 32);
    rs1 += __shfl_xor(rs1, 16); rs1 += __shfl_xor(rs1, 32);
    if (ff == 0 && l < 16) { rsred[kf][0][l] = rs0; rsred[kf][1][l] = rs1; }
    // partials: C[feat][i] -> tpart[kf][i][feat] (b128 per frag)
#pragma unroll
    for (int fa = 0; fa < 4; fa++) {
        *(float4*)&tpart[kf][li][ff * 64 + fa * 16 + q * 4] =
            (float4){acc[fa][0][0], acc[fa][0][1], acc[fa][0][2], acc[fa][0][3]};
        *(float4*)&tpart[kf][16 + li][ff * 64 + fa * 16 + q * 4] =
            (float4){acc[fa][1][0], acc[fa][1][1], acc[fa][1][2], acc[fa][1][3]};
    }
    __syncthreads();
    if (t < 32) {
        float rsum = rsred[0][t >> 4][t & 15] + rsred[1][t >> 4][t & 15] +
                     rsred[2][t >> 4][t & 15] + rsred[3][t >> 4][t & 15];
        rscl[t] = FDDb[2 * (i0 + t) + 1] / fmaxf(rsum, 1e-30f);
    }
    {   // sum 4 k-parts into tpart[0]
        int r = t >> 4, c0 = (t & 15) * 8;
#pragma unroll
        for (int hx = 0; hx < 2; hx++) {
            int c = c0 + hx * 4;
            float4 v0 = *(const float4*)&tpart[0][r][c];
            float4 v1 = *(const float4*)&tpart[1][r][c];
            float4 v2 = *(const float4*)&tpart[2][r][c];
            float4 v3 = *(const float4*)&tpart[3][r][c];
            v0.x += v1.x + v2.x + v3.x; v0.y += v1.y + v2.y + v3.y;
            v0.z += v1.z + v2.z + v3.z; v0.w += v1.w + v2.w + v3.w;
            *(float4*)&tpart[0][r][c] = v0;
        }
    }
    __syncthreads();
    // ---- R4 epilogue: GEMM1 T@W1 -> o1 ; dots2 ; GEMM2 o1@W2 -> OW2T ------
    const int c0w = wv * 32;
    f32x4 p00 = zero, p01 = zero, p10 = zero, p11 = zero;
    for (int k2 = 0; k2 < 4; ++k2) {
        s16x8 a2f[2];
#pragma unroll
        for (int mt = 0; mt < 2; ++mt) {
            const float* tp = &tpart[0][mt * 16 + li][k2 * 32 + q * 8];
            float4 t0 = *(const float4*)tp;
            float4 t1 = *(const float4*)(tp + 4);
            s16x8 aa;
            aa[0] = (short)f2bf(t0.x); aa[1] = (short)f2bf(t0.y);
            aa[2] = (short)f2bf(t0.z); aa[3] = (short)f2bf(t0.w);
            aa[4] = (short)f2bf(t1.x); aa[5] = (short)f2bf(t1.y);
            aa[6] = (short)f2bf(t1.z); aa[7] = (short)f2bf(t1.w);
            a2f[mt] = aa;
        }
        s16x8 w0 = *(const s16x8*)&W1T[(size_t)(c0w + li) * NF + k2 * 32 + q * 8];
        s16x8 w1 = *(const s16x8*)&W1T[(size_t)(c0w + 16 + li) * NF + k2 * 32 + q * 8];
        p00 = __builtin_amdgcn_mfma_f32_16x16x32_bf16(a2f[0], w0, p00, 0, 0, 0);
        p01 = __builtin_amdgcn_mfma_f32_16x16x32_bf16(a2f[0], w1, p01, 0, 0, 0);
        p10 = __builtin_amdgcn_mfma_f32_16x16x32_bf16(a2f[1], w0, p10, 0, 0, 0);
        p11 = __builtin_amdgcn_mfma_f32_16x16x32_bf16(a2f[1], w1, p11, 0, 0, 0);
    }
    __syncthreads();   // all tpart[0] reads done; o1 region (tpart[2..3]) free
#pragma unroll
    for (int mt = 0; mt < 2; ++mt) {
        f32x4 pa = mt ? p10 : p00;
        f32x4 pb = mt ? p11 : p01;
#pragma unroll
        for (int r = 0; r < 4; r++) {
            int rr = mt * 16 + q * 4 + r;
            float rsc = rscl[rr];
            int ca = c0w + li, cb2 = c0w + 16 + li;
            o1[rr * 260 + ca]  = fmaxf(pa[r] * rsc + b1[ca], 0.f);
            o1[rr * 260 + cb2] = fmaxf(pb[r] * rsc + b1[cb2], 0.f);
        }
    }
    __syncthreads();
    {   // dots2: 32 rows x 16 segs of 16 cols
        int r = t >> 4, seg = t & 15;
        float ps = 0.f, pd = 0.f;
#pragma unroll
        for (int qq = 0; qq < 4; qq++) {
            float4 xv = *(const float4*)&o1[r * 260 + seg * 16 + qq * 4];
            float4 sv = *(const float4*)&a2s[seg * 16 + qq * 4];
            float4 dv = *(const float4*)&a2d[seg * 16 + qq * 4];
            ps += xv.x * sv.x + xv.y * sv.y + xv.z * sv.z + xv.w * sv.w;
            pd += xv.x * dv.x + xv.y * dv.y + xv.z * dv.z + xv.w * dv.w;
        }
        dredp[(r * 16 + seg) * 2]     = ps;
        dredp[(r * 16 + seg) * 2 + 1] = pd;
    }
    {   // GEMM2: OW2T[c][node] = (o1 @ W2)^T ; wave (mt = wv&1, nt = wv>>1)
        const int mt = wv & 1, nt = wv >> 1;
        f32x4 q0 = zero;
        for (int k2 = 0; k2 < 8; ++k2) {
            int kc = k2 * 32 + q * 8;
            const float* op = &o1[(mt * 16 + li) * 260 + kc];
            float4 v0 = *(const float4*)op;
            float4 v1 = *(const float4*)(op + 4);
            s16x8 aa;
            aa[0] = (short)f2bf(v0.x); aa[1] = (short)f2bf(v0.y);
            aa[2] = (short)f2bf(v0.z); aa[3] = (short)f2bf(v0.w);
            aa[4] = (short)f2bf(v1.x); aa[5] = (short)f2bf(v1.y);
            aa[6] = (short)f2bf(v1.z); aa[7] = (short)f2bf(v1.w);
            s16x8 bb = *(const s16x8*)&W2T[(size_t)(nt * 16 + li) * NH + kc];
            q0 = __builtin_amdgcn_mfma_f32_16x16x32_bf16(aa, bb, q0, 0, 0, 0);
        }
        int c = nt * 16 + li;
        uint2 pk;
        pk.x = (u32)f2bf(q0[0]) | ((u32)f2bf(q0[1]) << 16);
        pk.y = (u32)f2bf(q0[2]) | ((u32)f2bf(q0[3]) << 16);
        *(uint2*)&OW2T[((size_t)b * NC + c) * NN + i0 + mt * 16 + q * 4] = pk;
    }
    __syncthreads();
    if (t < 64) {
        int r = t & 31, which = t >> 5;
        float s = 0.f;
#pragma unroll
        for (int seg = 0; seg < 16; ++seg) s += dredp[(r * 16 + seg) * 2 + which];
        if (which == 0) FS2[(b << 11) + i0 + r]        = s * LOG2E;
        else            FDD2[2 * ((b << 11) + i0 + r)] = s * LOG2E;
    }
}

// ---- kdense2: layer2 SpMM (no-barrier K-loop); node + graph partials -------
__global__ __launch_bounds__(512) void kdense2(
    const u64* __restrict__ bm, const float* __restrict__ FS,
    const float* __restrict__ FDD, const u16* __restrict__ OW2T,
    const float* __restrict__ b2, float* __restrict__ node,
    float* __restrict__ gpart) {
    const int b = blockIdx.y;
    const int i0 = blockIdx.x * 32;
    const int t = threadIdx.x, wv = t >> 6, l = t & 63;
    const int li = l & 15, q = l >> 4;

    __shared__ __attribute__((aligned(16))) float tp[8][32][68];      // 69.6KB
    __shared__ __attribute__((aligned(16))) float2 fdp[2048];
    __shared__ __attribute__((aligned(16))) u32 bmt[32][68];
    __shared__ float rsred[8][2][16];
    __shared__ float rscl[32];

    const float* FDDb = FDD + ((size_t)(b << 11) << 1);
    {
        const float4* src = (const float4*)FDDb;
        float4* dst = (float4*)fdp;
        dst[t] = src[t]; dst[t + 512] = src[t + 512];
    }
    {
        int r = t >> 4, seg = t & 15;
        const uint4* src = (const uint4*)(bm + ((size_t)((b << 11) + i0 + r)) * 32);
        *(uint4*)&bmt[r][seg * 4] = src[seg];
    }
    __syncthreads();

    const float fs0 = FS[(b << 11) + i0 + li];
    const float fs1 = FS[(b << 11) + i0 + 16 + li];
    const int irow0 = i0 + li, irow1 = i0 + 16 + li;
    const u16* Ob = OW2T + (size_t)b * NC * NN;
    const u16* obase = Ob + (size_t)li * NN + q * 8;

    f32x4 zero = {0.f, 0.f, 0.f, 0.f};
    f32x4 acc[4][2];
#pragma unroll
    for (int fa = 0; fa < 4; fa++) { acc[fa][0] = zero; acc[fa][1] = zero; }
    float rs0 = 0.f, rs1 = 0.f;

    for (int s = 0; s < 8; ++s) {
        const int kb = (wv * 8 + s) * 32;
        s16x8 xa0 = *(const s16x8*)(obase + kb);
        s16x8 xa1 = *(const s16x8*)(obase + (size_t)16 * NN + kb);
        s16x8 xa2 = *(const s16x8*)(obase + (size_t)32 * NN + kb);
        s16x8 xa3 = *(const s16x8*)(obase + (size_t)48 * NN + kb);
        const float4* fp4 = (const float4*)&fdp[kb + q * 8];
        float4 f0 = fp4[0], f1 = fp4[1], f2v = fp4[2], f3v = fp4[3];
        u32 m0 = (bmt[li][kb >> 5]      >> (q * 8)) & 0xffu;
        u32 m1 = (bmt[16 + li][kb >> 5] >> (q * 8)) & 0xffu;
        const int jb = kb + q * 8;
        s16x8 bw0, bw1;
        MKW(fs0, irow0, m0, bw0, rs0);
        MKW(fs1, irow1, m1, bw1, rs1);
        acc[0][0] = __builtin_amdgcn_mfma_f32_16x16x32_bf16(xa0, bw0, acc[0][0], 0, 0, 0);
        acc[1][0] = __builtin_amdgcn_mfma_f32_16x16x32_bf16(xa1, bw0, acc[1][0], 0, 0, 0);
        acc[2][0] = __builtin_amdgcn_mfma_f32_16x16x32_bf16(xa2, bw0, acc[2][0], 0, 0, 0);
        acc[3][0] = __builtin_amdgcn_mfma_f32_16x16x32_bf16(xa3, bw0, acc[3][0], 0, 0, 0);
        acc[0][1] = __builtin_amdgcn_mfma_f32_16x16x32_bf16(xa0, bw1, acc[0][1], 0, 0, 0);
        acc[1][1] = __builtin_amdgcn_mfma_f32_16x16x32_bf16(xa1, bw1, acc[1][1], 0, 0, 0);
        acc[2][1] = __builtin_amdgcn_mfma_f32_16x16x32_bf16(xa2, bw1, acc[2][1], 0, 0, 0);
        acc[3][1] = __builtin_amdgcn_mfma_f32_16x16x32_bf16(xa3, bw1, acc[3][1], 0, 0, 0);
    }
    rs0 += __shfl_xor(rs0, 16); rs0 += __shfl_xor(rs0, 32);
    rs1 += __shfl_xor(rs1, 16); rs1 += __shfl_xor(rs1, 32);
    if (l < 16) { rsred[wv][0][l] = rs0; rsred[wv][1][l] = rs1; }
#pragma unroll
    for (int fa = 0; fa < 4; fa++) {
        *(float4*)&tp[wv][li][fa * 16 + q * 4] =
            (float4){acc[fa][0][0], acc[fa][0][1], acc[fa][0][2], acc[fa][0][3]};
        *(float4*)&tp[wv][16 + li][fa * 16 + q * 4] =
            (float4){acc[fa][1][0], acc[fa][1][1], acc[fa][1][2], acc[fa][1][3]};
    }
    __syncthreads();
    if (t < 32) {
        float rsum = 0.f;
#pragma unroll
        for (int w8 = 0; w8 < 8; w8++) rsum += rsred[w8][t >> 4][t & 15];
        rscl[t] = FDDb[2 * (i0 + t) + 1] / fmaxf(rsum, 1e-30f);
    }
    {   // sum 8 parts into tp[0]
        int r = t >> 4, c0 = (t & 15) * 4;
        float4 v = *(const float4*)&tp[0][r][c0];
#pragma unroll
        for (int w8 = 1; w8 < 8; w8++) {
            float4 u = *(const float4*)&tp[w8][r][c0];
            v.x += u.x; v.y += u.y; v.z += u.z; v.w += u.w;
        }
        *(float4*)&tp[0][r][c0] = v;
    }
    __syncthreads();
    {   // scale + bias, store node, write back for graph partial
        int r = t >> 4, c0 = (t & 15) * 4;
        float rsc = rscl[r];
        float4 v = *(const float4*)&tp[0][r][c0];
        float4 bb = *(const float4*)&b2[c0];
        v.x = v.x * rsc + bb.x; v.y = v.y * rsc + bb.y;
        v.z = v.z * rsc + bb.z; v.w = v.w * rsc + bb.w;
        *(float4*)&node[((size_t)(b << 11) + i0 + r) * NC + c0] = v;
        *(float4*)&tp[0][r][c0] = v;
    }
    __syncthreads();
    if (t < NC) {
        float s = 0.f;
#pragma unroll
        for (int r = 0; r < 32; ++r) s += tp[0][r][t];
        gpart[(((size_t)b * (NN / 32)) + blockIdx.x) * NC + t] = s;
    }
}

// ---- graph scores: reduce per-block partials -------------------------------
__global__ void kgraph2(const float* __restrict__ gpart, float* __restrict__ graph) {
    int b = blockIdx.x;
    int c = threadIdx.x & 63, ch = threadIdx.x >> 6;
    float s = 0.f;
    for (int p = ch; p < NN / 32; p += 4)
        s += gpart[(((size_t)b * (NN / 32)) + p) * NC + c];
    __shared__ float red[4][64];
    red[ch][c] = s;
    __syncthreads();
    if (ch == 0) graph[b * NC + c] = red[0][c] + red[1][c] + red[2][c] + red[3][c];
}

extern "C" void kernel_launch(void* const* d_in, const int* in_sizes, int n_in,
                              void* d_out, int out_size, void* d_ws, size_t ws_size,
                              hipStream_t stream) {
    const float* X   = (const float*)d_in[0];
    const float* A   = (const float*)d_in[1];
    const float* a1s = (const float*)d_in[2];
    const float* a1d = (const float*)d_in[3];
    const float* W1  = (const float*)d_in[4];
    const float* b1  = (const float*)d_in[5];
    const float* a2s = (const float*)d_in[6];
    const float* a2d = (const float*)d_in[7];
    const float* W2  = (const float*)d_in[8];
    const float* b2  = (const float*)d_in[9];

    float* node  = (float*)d_out;                 // [4][2048][64]
    float* graph = node + (size_t)NB * NN * NC;   // [4][64]

    char* w = (char*)d_ws;
    float* FS1  = (float*)w; w += NB * NN * 4;
    float* FDD1 = (float*)w; w += NB * NN * 8;    // (fd1_j, d_j)
    float* FS2  = (float*)w; w += NB * NN * 4;
    float* FDD2 = (float*)w; w += NB * NN * 8;    // (fd2_j, d_j)
    u64*  bm    = (u64*)w;  w += (size_t)NB * NN * 32 * 8;           // 2 MB
    u16*  XT    = (u16*)w;  w += (size_t)NB * NF * NN * 2;           // 2 MB
    u16*  OW2T  = (u16*)w;  w += (size_t)NB * NC * NN * 2;           // 1 MB
    u16*  W1T   = (u16*)w;  w += NH * NF * 2;
    u16*  W2T   = (u16*)w;  w += NC * NH * 2;
    float* gpart = (float*)w; w += (size_t)NB * (NN / 32) * NC * 4;  // 64 KB

    kpre    <<<NB * 64 + 4 + NB * NN, 256, 0, stream>>>(X, A, a1s, a1d, W1, W2,
                                                        XT, W1T, W2T, FS1,
                                                        FDD1, FDD2, bm);
    kdense1 <<<dim3(NN / 32, NB), 512, 0, stream>>>(bm, FS1, FDD1, XT, W1T, W2T,
                                                    b1, a2s, a2d, FS2, FDD2, OW2T);
    kdense2 <<<dim3(NN / 32, NB), 512, 0, stream>>>(bm, FS2, FDD2, OW2T, b2,
                                                    node, gpart);
    kgraph2 <<<NB, 256, 0, stream>>>(gpart, graph);
}

// Round 10
// 75.992 us; speedup vs baseline: 1.3437x; 1.0007x over previous
//
#include <hip/hip_runtime.h>

// ---------------------------------------------------------------------------
// TwoLayerGCN on MI355X (gfx950).  B=4, N=2048, F=128, H=256, C=64.
//
//   d_i = rsqrt(nnz_i + 1) ; w_ij = [A_ij>0] exp(lrelu(fs_i+fd_j)) d_j (1+[i==j])
//   rs_i = sum_j [A_ij>0] exp(lrelu(fs_i+fd_j))
//   layer1: out1 = relu( (d_i/rs_i)(W@X)@W1 + b1 )
//   layer2: node = (d_i/rs_i) W2mat@(out1@W2) + b2 ; graph = sum_i node
//
// R9: dense MFMA SpMM, ZERO barriers in K-loop (operand swap: A=XT feats,
//     B=w computed per-lane in registers; K split across waves; one final
//     LDS slab reduction). 102 -> 76us.
// R10: A-frag loads were 16 rows x 4KB-stride scatter (64 cache lines /
//     instruction). XT and OW2T now stored FRAG-TILED: each 16x32 bf16 MFMA
//     fragment is a contiguous 1KB tile [li][32]; a frag load is a contiguous
//     1KB wave read (16 lines, 4-lane coalescing) -> 4x fewer TA requests.
// ---------------------------------------------------------------------------

typedef __attribute__((ext_vector_type(8))) short  s16x8;
typedef __attribute__((ext_vector_type(4))) float  f32x4;
typedef unsigned short u16;
typedef unsigned int   u32;
typedef unsigned long long u64;

#define LOG2E 1.4426950408889634f
#define NB 4
#define NN 2048
#define NF 128
#define NH 256
#define NC 64

__device__ __forceinline__ u16 f2bf(float f) {
    u32 x = __builtin_bit_cast(u32, f);
    return (u16)((x + 0x7fffu + ((x >> 16) & 1u)) >> 16);
}

// ---- kpre: block-role dispatch ---------------------------------------------
// [0,256): X-tiles -> XTf (frag-tiled bf16) + layer1 dots (FS1, FDD1.x).
// [256,260): W1T/W2T transposes.
// [260,260+8192): stats: A read -> bm bitmask, deg -> FDD1.y & FDD2.y.
__global__ void kpre(const float* __restrict__ X, const float* __restrict__ A,
                     const float* __restrict__ a1s, const float* __restrict__ a1d,
                     const float* __restrict__ W1, const float* __restrict__ W2,
                     u16* __restrict__ XTf, u16* __restrict__ W1T,
                     u16* __restrict__ W2T, float* __restrict__ FS1,
                     float* __restrict__ FDD1, float* __restrict__ FDD2,
                     u64* __restrict__ bm) {
    const int bid = blockIdx.x;
    const int t = threadIdx.x;
    if (bid >= NB * 64 + 4) {                 // ---- stats role ----
        __shared__ u64 masks[32];
        int row = bid - (NB * 64 + 4);        // 0..8191
        const float* Arow = A + (size_t)row * NN;
        int l = t & 63, wv = t >> 6;
#pragma unroll
        for (int e = 0; e < 8; e++) {
            float a = Arow[e * 256 + t];
            u64 m = __ballot(a > 0.f);
            if (l == 0) { masks[e * 4 + wv] = m; bm[(size_t)row * 32 + e * 4 + wv] = m; }
        }
        __syncthreads();
        if (t == 0) {
            u32 s = 0;
#pragma unroll
            for (int m = 0; m < 32; m++) s += __popcll(masks[m]);
            float d = rsqrtf((float)s + 1.0f);
            FDD1[2 * row + 1] = d;
            FDD2[2 * row + 1] = d;
        }
        return;
    }
    if (bid >= NB * 64) {                     // ---- weight role ----
        int tt = (bid - NB * 64) * 256 + t;
        for (int i = tt; i < NF * NH; i += 1024) {
            int k = i >> 8, c = i & 255;
            W1T[c * NF + k] = f2bf(W1[i]);
        }
        for (int i = tt; i < NH * NC; i += 1024) {
            int k = i >> 6, c = i & 63;
            W2T[c * NH + k] = f2bf(W2[i]);
        }
        return;
    }
    // ---- X role: 32 nodes (one k-block) ----
    __shared__ float tile[32][132];
    __shared__ float asb[NF], adb[NF];
    __shared__ float dred[32][8][2];
    const int b = bid >> 6, i0 = (bid & 63) * 32;
    if (t < 128) asb[t] = a1s[t];
    else         adb[t - 128] = a1d[t - 128];
    for (int i = t; i < 32 * NF; i += 256) {
        int r = i >> 7, c = i & 127;
        tile[r][c] = X[((size_t)b * NN + i0 + r) * NF + c];
    }
    __syncthreads();
    {   // layer1 dots
        int r = t >> 3, ch = t & 7;
        float ps = 0.f, pd = 0.f;
#pragma unroll
        for (int q = 0; q < 16; q++) {
            float x = tile[r][ch * 16 + q];
            ps += x * asb[ch * 16 + q];
            pd += x * adb[ch * 16 + q];
        }
        dred[r][ch][0] = ps; dred[r][ch][1] = pd;
    }
    {   // XTf frag-tiled write: frag f holds feats 16f..16f+15, tile [li][32 k]
        int f = t >> 5, li = (t >> 1) & 15, half = t & 1;
        __attribute__((aligned(16))) u16 tmp[16];
#pragma unroll
        for (int k = 0; k < 16; k++)
            tmp[k] = f2bf(tile[half * 16 + k][f * 16 + li]);
        u16* dst = XTf + ((size_t)(b * 8 + f) * 64 + (i0 >> 5)) * 512
                       + li * 32 + half * 16;
        int4* d4 = (int4*)dst;
        const int4* sv = (const int4*)tmp;
        d4[0] = sv[0]; d4[1] = sv[1];
    }
    __syncthreads();
    if (t < 64) {
        int r = t & 31, which = t >> 5;
        float s = 0.f;
#pragma unroll
        for (int ch = 0; ch < 8; ch++) s += dred[r][ch][which];
        int grow = (b << 11) + i0 + r;
        if (which == 0) FS1[grow] = s * LOG2E;
        else            FDD1[2 * grow] = s * LOG2E;
    }
}

// w B-fragment: 8 w values for row IR (batch-local), j = jb..jb+7.
#define MKW(FS_, IR_, M_, BW_, RS_) { \
    float fd_[8] = {f0.x, f0.z, f1.x, f1.z, f2v.x, f2v.z, f3v.x, f3v.z}; \
    float dd_[8] = {f0.y, f0.w, f1.y, f1.w, f2v.y, f2v.w, f3v.y, f3v.w}; \
    _Pragma("unroll") \
    for (int e = 0; e < 8; e++) { \
        float s_ = FS_ + fd_[e]; \
        float e_ = exp2f(fmaxf(s_, 0.2f * s_)); \
        bool mk = (M_ >> e) & 1u; \
        RS_ += mk ? e_ : 0.f; \
        float w_ = e_ * dd_[e]; \
        if (jb + e == IR_) w_ *= 2.f; \
        BW_[e] = mk ? (short)f2bf(w_) : (short)0; } }

// ---- kdense1: layer1 SpMM (no-barrier K-loop) + R4 epilogue ----------------
__global__ __launch_bounds__(512) void kdense1(
    const u64* __restrict__ bm, const float* __restrict__ FS,
    const float* __restrict__ FDD, const u16* __restrict__ XTf,
    const u16* __restrict__ W1T, const u16* __restrict__ W2T,
    const float* __restrict__ b1, const float* __restrict__ a2s,
    const float* __restrict__ a2d, float* __restrict__ FS2,
    float* __restrict__ FDD2, u16* __restrict__ OW2f) {
    const int b = blockIdx.y;
    const int i0 = blockIdx.x * 32;
    const int t = threadIdx.x, wv = t >> 6, l = t & 63;
    const int li = l & 15, q = l >> 4;
    const int kf = wv >> 1, ff = wv & 1;

    __shared__ __attribute__((aligned(16))) float tpart[4][32][132];  // 67.6KB
    float* o1 = &tpart[2][0][0];            // [32][260] aliases tpart[2..3]
    __shared__ __attribute__((aligned(16))) float2 fdp[2048];         // 16KB
    __shared__ __attribute__((aligned(16))) u32 bmt[32][68];          // 8.7KB
    __shared__ float rsred[4][2][16];
    __shared__ float rscl[32];
    __shared__ float dredp[1024];

    const float* FDDb = FDD + ((size_t)(b << 11) << 1);
    {   // stage fd/d panel
        const float4* src = (const float4*)FDDb;
        float4* dst = (float4*)fdp;
        dst[t] = src[t]; dst[t + 512] = src[t + 512];
    }
    {   // stage bm tile: 32 rows x 256B, padded stride 68 u32
        int r = t >> 4, seg = t & 15;
        const uint4* src = (const uint4*)(bm + ((size_t)((b << 11) + i0 + r)) * 32);
        *(uint4*)&bmt[r][seg * 4] = src[seg];
    }
    __syncthreads();

    const float fs0 = FS[(b << 11) + i0 + li];
    const float fs1 = FS[(b << 11) + i0 + 16 + li];
    const int irow0 = i0 + li, irow1 = i0 + 16 + li;
    const u16* xfb = XTf + (size_t)b * 8 * 64 * 512;
    const int laneoff = li * 32 + q * 8;      // lane offset within 1KB frag tile

    f32x4 zero = {0.f, 0.f, 0.f, 0.f};
    f32x4 acc[4][2];
#pragma unroll
    for (int fa = 0; fa < 4; fa++) { acc[fa][0] = zero; acc[fa][1] = zero; }
    float rs0 = 0.f, rs1 = 0.f;

    for (int s = 0; s < 16; ++s) {
        const int kblk = kf * 16 + s;
        const int kb = kblk * 32;
        const u16* xt = xfb + ((size_t)(ff * 4) * 64 + kblk) * 512 + laneoff;
        s16x8 xa0 = *(const s16x8*)(xt);
        s16x8 xa1 = *(const s16x8*)(xt + 64 * 512);
        s16x8 xa2 = *(const s16x8*)(xt + 128 * 512);
        s16x8 xa3 = *(const s16x8*)(xt + 192 * 512);
        const float4* fp4 = (const float4*)&fdp[kb + q * 8];
        float4 f0 = fp4[0], f1 = fp4[1], f2v = fp4[2], f3v = fp4[3];
        u32 m0 = (bmt[li][kb >> 5]      >> (q * 8)) & 0xffu;
        u32 m1 = (bmt[16 + li][kb >> 5] >> (q * 8)) & 0xffu;
        const int jb = kb + q * 8;
        s16x8 bw0, bw1;
        MKW(fs0, irow0, m0, bw0, rs0);
        MKW(fs1, irow1, m1, bw1, rs1);
        acc[0][0] = __builtin_amdgcn_mfma_f32_16x16x32_bf16(xa0, bw0, acc[0][0], 0, 0, 0);
        acc[1][0] = __builtin_amdgcn_mfma_f32_16x16x32_bf16(xa1, bw0, acc[1][0], 0, 0, 0);
        acc[2][0] = __builtin_amdgcn_mfma_f32_16x16x32_bf16(xa2, bw0, acc[2][0], 0, 0, 0);
        acc[3][0] = __builtin_amdgcn_mfma_f32_16x16x32_bf16(xa3, bw0, acc[3][0], 0, 0, 0);
        acc[0][1] = __builtin_amdgcn_mfma_f32_16x16x32_bf16(xa0, bw1, acc[0][1], 0, 0, 0);
        acc[1][1] = __builtin_amdgcn_mfma_f32_16x16x32_bf16(xa1, bw1, acc[1][1], 0, 0, 0);
        acc[2][1] = __builtin_amdgcn_mfma_f32_16x16x32_bf16(xa2, bw1, acc[2][1], 0, 0, 0);
        acc[3][1] = __builtin_amdgcn_mfma_f32_16x16x32_bf16(xa3, bw1, acc[3][1], 0, 0, 0);
    }
    rs0 += __shfl_xor(rs0, 16); rs0 += __shfl_xor(rs0, 32);
    rs1 += __shfl_xor(rs1, 16); rs1 += __shfl_xor(rs1, 32);
    if (ff == 0 && l < 16) { rsred[kf][0][l] = rs0; rsred[kf][1][l] = rs1; }
    // partials: C[feat][i] -> tpart[kf][i][feat] (b128 per frag)
#pragma unroll
    for (int fa = 0; fa < 4; fa++) {
        *(float4*)&tpart[kf][li][ff * 64 + fa * 16 + q * 4] =
            (float4){acc[fa][0][0], acc[fa][0][1], acc[fa][0][2], acc[fa][0][3]};
        *(float4*)&tpart[kf][16 + li][ff * 64 + fa * 16 + q * 4] =
            (float4){acc[fa][1][0], acc[fa][1][1], acc[fa][1][2], acc[fa][1][3]};
    }
    __syncthreads();
    if (t < 32) {
        float rsum = rsred[0][t >> 4][t & 15] + rsred[1][t >> 4][t & 15] +
                     rsred[2][t >> 4][t & 15] + rsred[3][t >> 4][t & 15];
        rscl[t] = FDDb[2 * (i0 + t) + 1] / fmaxf(rsum, 1e-30f);
    }
    {   // sum 4 k-parts into tpart[0]
        int r = t >> 4, c0 = (t & 15) * 8;
#pragma unroll
        for (int hx = 0; hx < 2; hx++) {
            int c = c0 + hx * 4;
            float4 v0 = *(const float4*)&tpart[0][r][c];
            float4 v1 = *(const float4*)&tpart[1][r][c];
            float4 v2 = *(const float4*)&tpart[2][r][c];
            float4 v3 = *(const float4*)&tpart[3][r][c];
            v0.x += v1.x + v2.x + v3.x; v0.y += v1.y + v2.y + v3.y;
            v0.z += v1.z + v2.z + v3.z; v0.w += v1.w + v2.w + v3.w;
            *(float4*)&tpart[0][r][c] = v0;
        }
    }
    __syncthreads();
    // ---- epilogue: GEMM1 T@W1 -> o1 ; dots2 ; GEMM2 o1@W2 -> OW2f ---------
    const int c0w = wv * 32;
    f32x4 p00 = zero, p01 = zero, p10 = zero, p11 = zero;
    for (int k2 = 0; k2 < 4; ++k2) {
        s16x8 a2f[2];
#pragma unroll
        for (int mt = 0; mt < 2; ++mt) {
            const float* tp = &tpart[0][mt * 16 + li][k2 * 32 + q * 8];
            float4 t0 = *(const float4*)tp;
            float4 t1 = *(const float4*)(tp + 4);
            s16x8 aa;
            aa[0] = (short)f2bf(t0.x); aa[1] = (short)f2bf(t0.y);
            aa[2] = (short)f2bf(t0.z); aa[3] = (short)f2bf(t0.w);
            aa[4] = (short)f2bf(t1.x); aa[5] = (short)f2bf(t1.y);
            aa[6] = (short)f2bf(t1.z); aa[7] = (short)f2bf(t1.w);
            a2f[mt] = aa;
        }
        s16x8 w0 = *(const s16x8*)&W1T[(size_t)(c0w + li) * NF + k2 * 32 + q * 8];
        s16x8 w1 = *(const s16x8*)&W1T[(size_t)(c0w + 16 + li) * NF + k2 * 32 + q * 8];
        p00 = __builtin_amdgcn_mfma_f32_16x16x32_bf16(a2f[0], w0, p00, 0, 0, 0);
        p01 = __builtin_amdgcn_mfma_f32_16x16x32_bf16(a2f[0], w1, p01, 0, 0, 0);
        p10 = __builtin_amdgcn_mfma_f32_16x16x32_bf16(a2f[1], w0, p10, 0, 0, 0);
        p11 = __builtin_amdgcn_mfma_f32_16x16x32_bf16(a2f[1], w1, p11, 0, 0, 0);
    }
    __syncthreads();   // all tpart[0] reads done; o1 region (tpart[2..3]) free
#pragma unroll
    for (int mt = 0; mt < 2; ++mt) {
        f32x4 pa = mt ? p10 : p00;
        f32x4 pb = mt ? p11 : p01;
#pragma unroll
        for (int r = 0; r < 4; r++) {
            int rr = mt * 16 + q * 4 + r;
            float rsc = rscl[rr];
            int ca = c0w + li, cb2 = c0w + 16 + li;
            o1[rr * 260 + ca]  = fmaxf(pa[r] * rsc + b1[ca], 0.f);
            o1[rr * 260 + cb2] = fmaxf(pb[r] * rsc + b1[cb2], 0.f);
        }
    }
    __syncthreads();
    {   // dots2: 32 rows x 16 segs of 16 cols
        int r = t >> 4, seg = t & 15;
        float ps = 0.f, pd = 0.f;
#pragma unroll
        for (int qq = 0; qq < 4; qq++) {
            float4 xv = *(const float4*)&o1[r * 260 + seg * 16 + qq * 4];
            float4 sv = *(const float4*)&a2s[seg * 16 + qq * 4];
            float4 dv = *(const float4*)&a2d[seg * 16 + qq * 4];
            ps += xv.x * sv.x + xv.y * sv.y + xv.z * sv.z + xv.w * sv.w;
            pd += xv.x * dv.x + xv.y * dv.y + xv.z * dv.z + xv.w * dv.w;
        }
        dredp[(r * 16 + seg) * 2]     = ps;
        dredp[(r * 16 + seg) * 2 + 1] = pd;
    }
    {   // GEMM2 -> OW2f frag tiles: frag nt (c-rows), k = nodes of this block
        const int mt = wv & 1, nt = wv >> 1;
        f32x4 q0 = zero;
        for (int k2 = 0; k2 < 8; ++k2) {
            int kc = k2 * 32 + q * 8;
            const float* op = &o1[(mt * 16 + li) * 260 + kc];
            float4 v0 = *(const float4*)op;
            float4 v1 = *(const float4*)(op + 4);
            s16x8 aa;
            aa[0] = (short)f2bf(v0.x); aa[1] = (short)f2bf(v0.y);
            aa[2] = (short)f2bf(v0.z); aa[3] = (short)f2bf(v0.w);
            aa[4] = (short)f2bf(v1.x); aa[5] = (short)f2bf(v1.y);
            aa[6] = (short)f2bf(v1.z); aa[7] = (short)f2bf(v1.w);
            s16x8 bb = *(const s16x8*)&W2T[(size_t)(nt * 16 + li) * NH + kc];
            q0 = __builtin_amdgcn_mfma_f32_16x16x32_bf16(aa, bb, q0, 0, 0, 0);
        }
        u16* dst = OW2f + ((size_t)(b * 4 + nt) * 64 + (i0 >> 5)) * 512
                        + li * 32 + mt * 16 + q * 4;
        uint2 pk;
        pk.x = (u32)f2bf(q0[0]) | ((u32)f2bf(q0[1]) << 16);
        pk.y = (u32)f2bf(q0[2]) | ((u32)f2bf(q0[3]) << 16);
        *(uint2*)dst = pk;
    }
    __syncthreads();
    if (t < 64) {
        int r = t & 31, which = t >> 5;
        float s = 0.f;
#pragma unroll
        for (int seg = 0; seg < 16; ++seg) s += dredp[(r * 16 + seg) * 2 + which];
        if (which == 0) FS2[(b << 11) + i0 + r]        = s * LOG2E;
        else            FDD2[2 * ((b << 11) + i0 + r)] = s * LOG2E;
    }
}

// ---- kdense2: layer2 SpMM (no-barrier K-loop); node + graph partials -------
__global__ __launch_bounds__(512) void kdense2(
    const u64* __restrict__ bm, const float* __restrict__ FS,
    const float* __restrict__ FDD, const u16* __restrict__ OW2f,
    const float* __restrict__ b2, float* __restrict__ node,
    float* __restrict__ gpart) {
    const int b = blockIdx.y;
    const int i0 = blockIdx.x * 32;
    const int t = threadIdx.x, wv = t >> 6, l = t & 63;
    const int li = l & 15, q = l >> 4;

    __shared__ __attribute__((aligned(16))) float tp[8][32][68];      // 69.6KB
    __shared__ __attribute__((aligned(16))) float2 fdp[2048];
    __shared__ __attribute__((aligned(16))) u32 bmt[32][68];
    __shared__ float rsred[8][2][16];
    __shared__ float rscl[32];

    const float* FDDb = FDD + ((size_t)(b << 11) << 1);
    {
        const float4* src = (const float4*)FDDb;
        float4* dst = (float4*)fdp;
        dst[t] = src[t]; dst[t + 512] = src[t + 512];
    }
    {
        int r = t >> 4, seg = t & 15;
        const uint4* src = (const uint4*)(bm + ((size_t)((b << 11) + i0 + r)) * 32);
        *(uint4*)&bmt[r][seg * 4] = src[seg];
    }
    __syncthreads();

    const float fs0 = FS[(b << 11) + i0 + li];
    const float fs1 = FS[(b << 11) + i0 + 16 + li];
    const int irow0 = i0 + li, irow1 = i0 + 16 + li;
    const u16* ofb = OW2f + (size_t)b * 4 * 64 * 512;
    const int laneoff = li * 32 + q * 8;

    f32x4 zero = {0.f, 0.f, 0.f, 0.f};
    f32x4 acc[4][2];
#pragma unroll
    for (int fa = 0; fa < 4; fa++) { acc[fa][0] = zero; acc[fa][1] = zero; }
    float rs0 = 0.f, rs1 = 0.f;

    for (int s = 0; s < 8; ++s) {
        const int kblk = wv * 8 + s;
        const int kb = kblk * 32;
        const u16* ot = ofb + (size_t)kblk * 512 + laneoff;
        s16x8 xa0 = *(const s16x8*)(ot);
        s16x8 xa1 = *(const s16x8*)(ot + 64 * 512);
        s16x8 xa2 = *(const s16x8*)(ot + 128 * 512);
        s16x8 xa3 = *(const s16x8*)(ot + 192 * 512);
        const float4* fp4 = (const float4*)&fdp[kb + q * 8];
        float4 f0 = fp4[0], f1 = fp4[1], f2v = fp4[2], f3v = fp4[3];
        u32 m0 = (bmt[li][kb >> 5]      >> (q * 8)) & 0xffu;
        u32 m1 = (bmt[16 + li][kb >> 5] >> (q * 8)) & 0xffu;
        const int jb = kb + q * 8;
        s16x8 bw0, bw1;
        MKW(fs0, irow0, m0, bw0, rs0);
        MKW(fs1, irow1, m1, bw1, rs1);
        acc[0][0] = __builtin_amdgcn_mfma_f32_16x16x32_bf16(xa0, bw0, acc[0][0], 0, 0, 0);
        acc[1][0] = __builtin_amdgcn_mfma_f32_16x16x32_bf16(xa1, bw0, acc[1][0], 0, 0, 0);
        acc[2][0] = __builtin_amdgcn_mfma_f32_16x16x32_bf16(xa2, bw0, acc[2][0], 0, 0, 0);
        acc[3][0] = __builtin_amdgcn_mfma_f32_16x16x32_bf16(xa3, bw0, acc[3][0], 0, 0, 0);
        acc[0][1] = __builtin_amdgcn_mfma_f32_16x16x32_bf16(xa0, bw1, acc[0][1], 0, 0, 0);
        acc[1][1] = __builtin_amdgcn_mfma_f32_16x16x32_bf16(xa1, bw1, acc[1][1], 0, 0, 0);
        acc[2][1] = __builtin_amdgcn_mfma_f32_16x16x32_bf16(xa2, bw1, acc[2][1], 0, 0, 0);
        acc[3][1] = __builtin_amdgcn_mfma_f32_16x16x32_bf16(xa3, bw1, acc[3][1], 0, 0, 0);
    }
    rs0 += __shfl_xor(rs0, 16); rs0 += __shfl_xor(rs0, 32);
    rs1 += __shfl_xor(rs1, 16); rs1 += __shfl_xor(rs1, 32);
    if (l < 16) { rsred[wv][0][l] = rs0; rsred[wv][1][l] = rs1; }
#pragma unroll
    for (int fa = 0; fa < 4; fa++) {
        *(float4*)&tp[wv][li][fa * 16 + q * 4] =
            (float4){acc[fa][0][0], acc[fa][0][1], acc[fa][0][2], acc[fa][0][3]};
        *(float4*)&tp[wv][16 + li][fa * 16 + q * 4] =
            (float4){acc[fa][1][0], acc[fa][1][1], acc[fa][1][2], acc[fa][1][3]};
    }
    __syncthreads();
    if (t < 32) {
        float rsum = 0.f;
#pragma unroll
        for (int w8 = 0; w8 < 8; w8++) rsum += rsred[w8][t >> 4][t & 15];
        rscl[t] = FDDb[2 * (i0 + t) + 1] / fmaxf(rsum, 1e-30f);
    }
    {   // sum 8 parts into tp[0]
        int r = t >> 4, c0 = (t & 15) * 4;
        float4 v = *(const float4*)&tp[0][r][c0];
#pragma unroll
        for (int w8 = 1; w8 < 8; w8++) {
            float4 u = *(const float4*)&tp[w8][r][c0];
            v.x += u.x; v.y += u.y; v.z += u.z; v.w += u.w;
        }
        *(float4*)&tp[0][r][c0] = v;
    }
    __syncthreads();
    {   // scale + bias, store node, write back for graph partial
        int r = t >> 4, c0 = (t & 15) * 4;
        float rsc = rscl[r];
        float4 v = *(const float4*)&tp[0][r][c0];
        float4 bb = *(const float4*)&b2[c0];
        v.x = v.x * rsc + bb.x; v.y = v.y * rsc + bb.y;
        v.z = v.z * rsc + bb.z; v.w = v.w * rsc + bb.w;
        *(float4*)&node[((size_t)(b << 11) + i0 + r) * NC + c0] = v;
        *(float4*)&tp[0][r][c0] = v;
    }
    __syncthreads();
    if (t < NC) {
        float s = 0.f;
#pragma unroll
        for (int r = 0; r < 32; ++r) s += tp[0][r][t];
        gpart[(((size_t)b * (NN / 32)) + blockIdx.x) * NC + t] = s;
    }
}

// ---- graph scores: reduce per-block partials -------------------------------
__global__ void kgraph2(const float* __restrict__ gpart, float* __restrict__ graph) {
    int b = blockIdx.x;
    int c = threadIdx.x & 63, ch = threadIdx.x >> 6;
    float s = 0.f;
    for (int p = ch; p < NN / 32; p += 4)
        s += gpart[(((size_t)b * (NN / 32)) + p) * NC + c];
    __shared__ float red[4][64];
    red[ch][c] = s;
    __syncthreads();
    if (ch == 0) graph[b * NC + c] = red[0][c] + red[1][c] + red[2][c] + red[3][c];
}

extern "C" void kernel_launch(void* const* d_in, const int* in_sizes, int n_in,
                              void* d_out, int out_size, void* d_ws, size_t ws_size,
                              hipStream_t stream) {
    const float* X   = (const float*)d_in[0];
    const float* A   = (const float*)d_in[1];
    const float* a1s = (const float*)d_in[2];
    const float* a1d = (const float*)d_in[3];
    const float* W1  = (const float*)d_in[4];
    const float* b1  = (const float*)d_in[5];
    const float* a2s = (const float*)d_in[6];
    const float* a2d = (const float*)d_in[7];
    const float* W2  = (const float*)d_in[8];
    const float* b2  = (const float*)d_in[9];

    float* node  = (float*)d_out;                 // [4][2048][64]
    float* graph = node + (size_t)NB * NN * NC;   // [4][64]

    char* w = (char*)d_ws;
    float* FS1  = (float*)w; w += NB * NN * 4;
    float* FDD1 = (float*)w; w += NB * NN * 8;    // (fd1_j, d_j)
    float* FS2  = (float*)w; w += NB * NN * 4;
    float* FDD2 = (float*)w; w += NB * NN * 8;    // (fd2_j, d_j)
    u64*  bm    = (u64*)w;  w += (size_t)NB * NN * 32 * 8;           // 2 MB
    u16*  XTf   = (u16*)w;  w += (size_t)NB * NF * NN * 2;           // 2 MB
    u16*  OW2f  = (u16*)w;  w += (size_t)NB * NC * NN * 2;           // 1 MB
    u16*  W1T   = (u16*)w;  w += NH * NF * 2;
    u16*  W2T   = (u16*)w;  w += NC * NH * 2;
    float* gpart = (float*)w; w += (size_t)NB * (NN / 32) * NC * 4;  // 64 KB

    kpre    <<<NB * 64 + 4 + NB * NN, 256, 0, stream>>>(X, A, a1s, a1d, W1, W2,
                                                        XTf, W1T, W2T, FS1,
                                                        FDD1, FDD2, bm);
    kdense1 <<<dim3(NN / 32, NB), 512, 0, stream>>>(bm, FS1, FDD1, XTf, W1T, W2T,
                                                    b1, a2s, a2d, FS2, FDD2, OW2f);
    kdense2 <<<dim3(NN / 32, NB), 512, 0, stream>>>(bm, FS2, FDD2, OW2f, b2,
                                                    node, gpart);
    kgraph2 <<<NB, 256, 0, stream>>>(gpart, graph);
}